// Round 5
// baseline (275.975 us; speedup 1.0000x reference)
//
#include <hip/hip_runtime.h>
#include <math.h>

// ---------------------------------------------------------------------------
// TimeAttender: S=2048, B=32, D=512, K=147
// out = concat(applied [B*D], norm_w [B*S])
//
// Math notes:
//  * prev_probs normalizer and softmax Z cancel in
//      norm_w = adj * exp(w) / sum_s(adj * exp(w))
//  * w = cosine in [-1,1] -> exp(w) in [0.37,2.72]: no max-subtraction,
//    single pass over e. w = dot * rsq(sq); sq==0 guard = safe-norm path.
//  * Ledger (R0..R4): fixed harness cost ~157 us (512MB poison fills +
//    resets); main ~50-55 us in EVERY layout; combine ~ partial_bytes /
//    access quality. Lessons:
//    - R2: last-block fusion w/ __threadfence = L2 writeback storm. NEVER.
//    - R3: occupancy 4->8 waves/SIMD, ILP batching: NEUTRAL.
//    - R4: contiguous-vs-strided e walk: NEUTRAL. Pattern is not the limit.
//  * Diagnosis: main is LITTLE'S-LAW bound: <=2 rows (4KB) in flight per
//    wave, VGPR_Count=44 (compiler had no room to pipeline), memory pipe
//    idle during each row's shfl/exp phase -> ~2.4 TB/s ceiling.
//  * This round: explicit depth — CH=16/wave, rows in double-buffered
//    groups of 4 (named regs only), launch_bounds(256,4) -> VGPR cap 128;
//    4-8 rows (8-16KB)/wave in flight continuously. Partial transposed to
//    [b][sx][d] so main writes / combine reads are contiguous.
// ---------------------------------------------------------------------------

__device__ __forceinline__ float wave_sum(float v) {
    for (int off = 32; off; off >>= 1) v += __shfl_xor(v, off);
    return v;
}

// ---------------------------------------------------------------------------
// K1: grid (1 + S/256, B), block 256. Role split on blockIdx.x:
//   bx == 0 : ns[b,:] = normalize(state[b,:] @ W^T + bias)  (safe-norm)
//   bx >= 1 : adj[b, s] = relu(conv1d_same(prev[b,:], cw)[s] + cb0)
// ---------------------------------------------------------------------------
__global__ __launch_bounds__(256) void front_kernel(
    const float* __restrict__ state, const float* __restrict__ W,
    const float* __restrict__ bias, const float* __restrict__ prev,
    const float* __restrict__ cw, const float* __restrict__ cb,
    float* __restrict__ ns, float* __restrict__ adj,
    int S, int D, int K) {
    __shared__ __align__(16) float smem[1024];
    __shared__ float red[4];
    int b = blockIdx.y;
    int t = threadIdx.x;
    int lane = t & 63, wv = t >> 6;

    if (blockIdx.x == 0) {
        // ---- linear + normalize: 256 threads x 2 dots of length 512 ----
        if (t < D / 4)
            ((float4*)smem)[t] = ((const float4*)(state + (size_t)b * D))[t];
        __syncthreads();
        const float4* sv = (const float4*)smem;
        float acc0 = bias[t];
        float acc1 = bias[t + 256];
        const float4* W0 = (const float4*)(W + (size_t)t * D);
        const float4* W1 = (const float4*)(W + (size_t)(t + 256) * D);
#pragma unroll 8
        for (int k = 0; k < 128; ++k) {
            float4 s4 = sv[k];
            float4 w0 = W0[k];
            float4 w1 = W1[k];
            acc0 += w0.x * s4.x + w0.y * s4.y + w0.z * s4.z + w0.w * s4.w;
            acc1 += w1.x * s4.x + w1.y * s4.y + w1.z * s4.z + w1.w * s4.w;
        }
        float sq = acc0 * acc0 + acc1 * acc1;
        sq = wave_sum(sq);
        if (lane == 0) red[wv] = sq;
        __syncthreads();
        float tot = red[0] + red[1] + red[2] + red[3];
        float inv = (tot > 0.f) ? __builtin_amdgcn_rsqf(tot) : 0.f;
        ns[(size_t)b * D + t] = acc0 * inv;
        ns[(size_t)b * D + t + 256] = acc1 * inv;
    } else {
        // ---- conv part ----
        int s0 = (blockIdx.x - 1) * 256;
        int pad = K / 2;
        int seglen = 256 + K - 1;
        float* seg = smem;            // seglen floats (<= 256+255)
        float* wk = smem + 512;       // K floats (<= 256)
        for (int i = t; i < seglen; i += 256) {
            int s = s0 - pad + i;
            seg[i] = (s >= 0 && s < S) ? prev[(size_t)b * S + s] : 0.f;
        }
        for (int j = t; j < K; j += 256) wk[j] = cw[j];
        __syncthreads();
        float y = cb[0];
        for (int j = 0; j < K; ++j) y += seg[t + j] * wk[j];
        adj[(size_t)b * S + s0 + t] = fmaxf(y, 0.f);
    }
}

// ---------------------------------------------------------------------------
// K2 (main): grid (S/16, B/4), block 256 = 4 waves, launch_bounds(256,4).
// Wave w of block (sx, by): b = by*4+w, rows s in [sx*16, sx*16+16).
// Rows processed in double-buffered groups of 4 (named regs): while group
// X computes (8 interleaved shfl chains -> coefs -> acc), the next 4 rows'
// 8 dwordx4 loads are in flight. 8-16 KB outstanding per wave at all times.
// ---------------------------------------------------------------------------
#define LOADG(Xa0, Xb0, Xa1, Xb1, Xa2, Xb2, Xa3, Xb3, base)                  \
    Xa0 = (base)[lane];                Xb0 = (base)[lane + 64];              \
    Xa1 = (base)[rstride + lane];      Xb1 = (base)[rstride + lane + 64];    \
    Xa2 = (base)[2 * rstride + lane];  Xb2 = (base)[2 * rstride + lane + 64];\
    Xa3 = (base)[3 * rstride + lane];  Xb3 = (base)[3 * rstride + lane + 64];

#define DOTSQ(d, q, Xa, Xb)                                                  \
    d = Xa.x * ns0.x + Xa.y * ns0.y + Xa.z * ns0.z + Xa.w * ns0.w            \
      + Xb.x * ns1.x + Xb.y * ns1.y + Xb.z * ns1.z + Xb.w * ns1.w;           \
    q = Xa.x * Xa.x + Xa.y * Xa.y + Xa.z * Xa.z + Xa.w * Xa.w                \
      + Xb.x * Xb.x + Xb.y * Xb.y + Xb.z * Xb.z + Xb.w * Xb.w;

#define PROC(gi, Xa0, Xb0, Xa1, Xb1, Xa2, Xb2, Xa3, Xb3)                     \
    {                                                                        \
        float d0, d1, d2, d3, q0, q1, q2, q3;                                \
        DOTSQ(d0, q0, Xa0, Xb0)                                              \
        DOTSQ(d1, q1, Xa1, Xb1)                                              \
        DOTSQ(d2, q2, Xa2, Xb2)                                              \
        DOTSQ(d3, q3, Xa3, Xb3)                                              \
        _Pragma("unroll")                                                    \
        for (int off = 32; off; off >>= 1) {                                 \
            d0 += __shfl_xor(d0, off); d1 += __shfl_xor(d1, off);            \
            d2 += __shfl_xor(d2, off); d3 += __shfl_xor(d3, off);            \
            q0 += __shfl_xor(q0, off); q1 += __shfl_xor(q1, off);            \
            q2 += __shfl_xor(q2, off); q3 += __shfl_xor(q3, off);            \
        }                                                                    \
        float r0 = (q0 > 0.f) ? __builtin_amdgcn_rsqf(q0) : 0.f;             \
        float r1 = (q1 > 0.f) ? __builtin_amdgcn_rsqf(q1) : 0.f;             \
        float r2 = (q2 > 0.f) ? __builtin_amdgcn_rsqf(q2) : 0.f;             \
        float r3 = (q3 > 0.f) ? __builtin_amdgcn_rsqf(q3) : 0.f;             \
        float c0 = __shfl(adjv, (gi))     * __expf(d0 * r0);                 \
        float c1 = __shfl(adjv, (gi) + 1) * __expf(d1 * r1);                 \
        float c2 = __shfl(adjv, (gi) + 2) * __expf(d2 * r2);                 \
        float c3 = __shfl(adjv, (gi) + 3) * __expf(d3 * r3);                 \
        if (lane == 0) {                                                     \
            float4 cv = {c0, c1, c2, c3};                                    \
            *((float4*)(u + (size_t)b * S + s0 + (gi))) = cv;                \
        }                                                                    \
        acc0.x += c0 * Xa0.x + c1 * Xa1.x + c2 * Xa2.x + c3 * Xa3.x;         \
        acc0.y += c0 * Xa0.y + c1 * Xa1.y + c2 * Xa2.y + c3 * Xa3.y;         \
        acc0.z += c0 * Xa0.z + c1 * Xa1.z + c2 * Xa2.z + c3 * Xa3.z;         \
        acc0.w += c0 * Xa0.w + c1 * Xa1.w + c2 * Xa2.w + c3 * Xa3.w;         \
        acc1.x += c0 * Xb0.x + c1 * Xb1.x + c2 * Xb2.x + c3 * Xb3.x;         \
        acc1.y += c0 * Xb0.y + c1 * Xb1.y + c2 * Xb2.y + c3 * Xb3.y;         \
        acc1.z += c0 * Xb0.z + c1 * Xb1.z + c2 * Xb2.z + c3 * Xb3.z;         \
        acc1.w += c0 * Xb0.w + c1 * Xb1.w + c2 * Xb2.w + c3 * Xb3.w;         \
        z += (c0 + c1) + (c2 + c3);                                          \
    }

__global__ __launch_bounds__(256, 4) void main_kernel(
    const float* __restrict__ e, const float* __restrict__ ns,
    const float* __restrict__ adj, float* __restrict__ partial,
    float* __restrict__ zbuf, float* __restrict__ u,
    int S, int B, int D) {
    constexpr int CH = 16;
    int wave = threadIdx.x >> 6;
    int lane = threadIdx.x & 63;
    int b = blockIdx.y * 4 + wave;
    int sx = blockIdx.x;
    int s0 = sx * CH;
    int NPART = gridDim.x;

    const float4* ns4 = (const float4*)(ns + (size_t)b * D);
    float4 ns0 = ns4[lane];
    float4 ns1 = ns4[lane + 64];

    float adjv = (lane < CH) ? adj[(size_t)b * S + s0 + lane] : 0.f;

    float4 acc0 = {0.f, 0.f, 0.f, 0.f};
    float4 acc1 = {0.f, 0.f, 0.f, 0.f};
    float z = 0.f;

    const float4* row4 = (const float4*)(e + ((size_t)s0 * B + b) * D);
    size_t rstride = (size_t)B * D / 4;   // float4 stride between s rows

    float4 Aa0, Ab0, Aa1, Ab1, Aa2, Ab2, Aa3, Ab3;
    float4 Ba0, Bb0, Ba1, Bb1, Ba2, Bb2, Ba3, Bb3;

    LOADG(Aa0, Ab0, Aa1, Ab1, Aa2, Ab2, Aa3, Ab3, row4)                 // 0-3
    LOADG(Ba0, Bb0, Ba1, Bb1, Ba2, Bb2, Ba3, Bb3, row4 + 4 * rstride)   // 4-7
    PROC(0, Aa0, Ab0, Aa1, Ab1, Aa2, Ab2, Aa3, Ab3)
    LOADG(Aa0, Ab0, Aa1, Ab1, Aa2, Ab2, Aa3, Ab3, row4 + 8 * rstride)   // 8-11
    PROC(4, Ba0, Bb0, Ba1, Bb1, Ba2, Bb2, Ba3, Bb3)
    LOADG(Ba0, Bb0, Ba1, Bb1, Ba2, Bb2, Ba3, Bb3, row4 + 12 * rstride)  // 12-15
    PROC(8, Aa0, Ab0, Aa1, Ab1, Aa2, Ab2, Aa3, Ab3)
    PROC(12, Ba0, Bb0, Ba1, Bb1, Ba2, Bb2, Ba3, Bb3)

    // per-wave partial: partial[b][sx][:] (contiguous for combine)
    float4* p4 = (float4*)(partial + ((size_t)b * NPART + sx) * D);
    p4[lane] = acc0;
    p4[lane + 64] = acc1;
    if (lane == 0) zbuf[(size_t)b * NPART + sx] = z;
}

// ---------------------------------------------------------------------------
// K3: grid (4, B), block 256. Block (q,b):
//   Z = sum_sx zbuf[b][sx]  (NPART<=256: one per thread, block reduce)
//   applied[b, q*128 .. +128) = sum_sx partial[b][sx][slice] / Z
//   norm_w[b, q*512 .. +512) = u[...] / Z
// ---------------------------------------------------------------------------
__global__ __launch_bounds__(256) void combine_kernel(
    const float* __restrict__ partial, const float* __restrict__ zbuf,
    const float* __restrict__ u, float* __restrict__ applied,
    float* __restrict__ norm_w, int S, int B, int D, int NPART) {
    int q = blockIdx.x;       // 0..3
    int b = blockIdx.y;
    int t = threadIdx.x;
    __shared__ __align__(16) float4 red4[8][32];
    __shared__ float zred[4];
    __shared__ float zsh;

    // Z reduce: one zbuf entry per thread (NPART <= 256), block reduce
    float zt = (t < NPART) ? zbuf[(size_t)b * NPART + t] : 0.f;
    zt = wave_sum(zt);
    if ((t & 63) == 0) zred[t >> 6] = zt;

    // applied quarter: 32 float4 columns, 8-way sx strata across threads
    int c2 = t >> 5;          // 0..7
    int di = t & 31;          // 0..31
    int d4 = q * 32 + di;     // float4 index into D/4 = 128
    const float4* p4 = (const float4*)partial;
    float4 a = {0.f, 0.f, 0.f, 0.f};
    for (int sx = c2; sx < NPART; sx += 8) {
        float4 x = p4[((size_t)b * NPART + sx) * (D >> 2) + d4];
        a.x += x.x; a.y += x.y; a.z += x.z; a.w += x.w;
    }
    red4[c2][di] = a;
    __syncthreads();
    if (t == 0) zsh = 1.f / (zred[0] + zred[1] + zred[2] + zred[3]);
    __syncthreads();
    float inv = zsh;
    if (t < 32) {
        float4 s = red4[0][t];
#pragma unroll
        for (int j = 1; j < 8; ++j) {
            float4 x = red4[j][t];
            s.x += x.x; s.y += x.y; s.z += x.z; s.w += x.w;
        }
        s.x *= inv; s.y *= inv; s.z *= inv; s.w *= inv;
        ((float4*)(applied + (size_t)b * D))[q * 32 + t] = s;
    }

    // norm_w quarter: 128 float4 per q-slice
    const float4* u4 = (const float4*)(u + (size_t)b * S);
    float4* nw4 = (float4*)(norm_w + (size_t)b * S);
    if (t < 128) {
        int idx = q * (S >> 4) + t;   // S/4 float4 per b, quarter = S/16
        float4 x = u4[idx];
        x.x *= inv; x.y *= inv; x.z *= inv; x.w *= inv;
        nw4[idx] = x;
    }
}

extern "C" void kernel_launch(void* const* d_in, const int* in_sizes, int n_in,
                              void* d_out, int out_size, void* d_ws, size_t ws_size,
                              hipStream_t stream) {
    const float* enc   = (const float*)d_in[0];  // [S,B,D]
    const float* state = (const float*)d_in[1];  // [B,D]
    const float* prev  = (const float*)d_in[2];  // [B,S]
    const float* W     = (const float*)d_in[3];  // [D,D]
    const float* bias  = (const float*)d_in[4];  // [D]
    const float* cw    = (const float*)d_in[5];  // [K]
    const float* cb    = (const float*)d_in[6];  // [1]

    const int S = in_sizes[0] / in_sizes[1];   // 2048
    const int B = in_sizes[2] / S;             // 32
    const int D = in_sizes[1] / B;             // 512
    const int K = in_sizes[5];                 // 147

    float* out     = (float*)d_out;
    float* applied = out;                    // B*D
    float* norm_w  = out + (size_t)B * D;    // B*S

    const int CH = 16;             // s-rows per wave (matches kernel constexpr)
    const int NPART = S / CH;      // 128 per-wave partials per batch row

    float* ws       = (float*)d_ws;
    float* nsbuf    = ws;                            // B*D
    float* adj      = nsbuf + (size_t)B * D;         // B*S
    float* u        = adj + (size_t)B * S;           // B*S
    float* zbuf     = u + (size_t)B * S;             // B*NPART
    float* partial  = zbuf + (size_t)B * NPART;      // B*NPART*D (8.4 MB)

    front_kernel<<<dim3(1 + S / 256, B), 256, 0, stream>>>(
        state, W, bias, prev, cw, cb, nsbuf, adj, S, D, K);
    main_kernel<<<dim3(S / CH, B / 4), 256, 0, stream>>>(
        enc, nsbuf, adj, partial, zbuf, u, S, B, D);
    combine_kernel<<<dim3(4, B), 256, 0, stream>>>(
        partial, zbuf, u, applied, norm_w, S, B, D, NPART);
}

// Round 6
// 250.860 us; speedup vs baseline: 1.1001x; 1.1001x over previous
//
#include <hip/hip_runtime.h>
#include <math.h>

// ---------------------------------------------------------------------------
// TimeAttender: S=2048, B=32, D=512, K=147
// out = concat(applied [B*D], norm_w [B*S])
//
// Math notes:
//  * prev_probs normalizer and softmax Z cancel in
//      norm_w = adj * exp(w) / sum_s(adj * exp(w))
//  * w = cosine in [-1,1] -> exp(w) in [0.37,2.72]: no max-subtraction,
//    single pass over e. w = dot * rsq(sq); sq==0 guard = safe-norm path.
//  * Ledger (R0..R5): fixed harness cost ~157 us (poison fills + resets).
//    main_kernel measured directly in R5: 2.3-2.5 TB/s, VALUBusy 6%,
//    occupancy 36% -> outstanding-bytes (Little's law) limited.
//    - R2: last-block fusion w/ __threadfence = L2 writeback storm. NEVER.
//    - R3: occupancy/ILP tweaks NEUTRAL. R4: contiguous-vs-strided NEUTRAL.
//    - R5: register-resident 16-row pipeline -> VGPR_Count 64, WRITE_SIZE
//      85.8 MB (~77 MB scratch spills!). Deep pipelines must NOT live in
//      VGPRs.
//  * This round: global_load_lds (fire-and-forget DMA, zero VGPR cost) +
//    counted s_waitcnt vmcnt(8) (never 0 until tail) + per-wave 3-buffer
//    LDS ring (2 rows x 2KB per buffer). 8-12 KB outstanding per wave
//    continuously; no barriers (buffers wave-private); compute reads back
//    via ds_read_b128. u coefs packed in regs, stored once at the end so
//    vmcnt counts only staging loads.
// ---------------------------------------------------------------------------

__device__ __forceinline__ float wave_sum(float v) {
    for (int off = 32; off; off >>= 1) v += __shfl_xor(v, off);
    return v;
}

__device__ __forceinline__ void gll16(const float4* g, float4* l) {
    __builtin_amdgcn_global_load_lds(
        (const __attribute__((address_space(1))) void*)g,
        (__attribute__((address_space(3))) void*)l, 16, 0, 0);
}

// ---------------------------------------------------------------------------
// K1: grid (1 + S/256, B), block 256. Role split on blockIdx.x:
//   bx == 0 : ns[b,:] = normalize(state[b,:] @ W^T + bias)  (safe-norm)
//   bx >= 1 : adj[b, s] = relu(conv1d_same(prev[b,:], cw)[s] + cb0)
// ---------------------------------------------------------------------------
__global__ __launch_bounds__(256) void front_kernel(
    const float* __restrict__ state, const float* __restrict__ W,
    const float* __restrict__ bias, const float* __restrict__ prev,
    const float* __restrict__ cw, const float* __restrict__ cb,
    float* __restrict__ ns, float* __restrict__ adj,
    int S, int D, int K) {
    __shared__ __align__(16) float smem[1024];
    __shared__ float red[4];
    int b = blockIdx.y;
    int t = threadIdx.x;
    int lane = t & 63, wv = t >> 6;

    if (blockIdx.x == 0) {
        // ---- linear + normalize: 256 threads x 2 dots of length 512 ----
        if (t < D / 4)
            ((float4*)smem)[t] = ((const float4*)(state + (size_t)b * D))[t];
        __syncthreads();
        const float4* sv = (const float4*)smem;
        float acc0 = bias[t];
        float acc1 = bias[t + 256];
        const float4* W0 = (const float4*)(W + (size_t)t * D);
        const float4* W1 = (const float4*)(W + (size_t)(t + 256) * D);
#pragma unroll 8
        for (int k = 0; k < 128; ++k) {
            float4 s4 = sv[k];
            float4 w0 = W0[k];
            float4 w1 = W1[k];
            acc0 += w0.x * s4.x + w0.y * s4.y + w0.z * s4.z + w0.w * s4.w;
            acc1 += w1.x * s4.x + w1.y * s4.y + w1.z * s4.z + w1.w * s4.w;
        }
        float sq = acc0 * acc0 + acc1 * acc1;
        sq = wave_sum(sq);
        if (lane == 0) red[wv] = sq;
        __syncthreads();
        float tot = red[0] + red[1] + red[2] + red[3];
        float inv = (tot > 0.f) ? __builtin_amdgcn_rsqf(tot) : 0.f;
        ns[(size_t)b * D + t] = acc0 * inv;
        ns[(size_t)b * D + t + 256] = acc1 * inv;
    } else {
        // ---- conv part ----
        int s0 = (blockIdx.x - 1) * 256;
        int pad = K / 2;
        int seglen = 256 + K - 1;
        float* seg = smem;            // seglen floats (<= 256+255)
        float* wk = smem + 512;       // K floats (<= 256)
        for (int i = t; i < seglen; i += 256) {
            int s = s0 - pad + i;
            seg[i] = (s >= 0 && s < S) ? prev[(size_t)b * S + s] : 0.f;
        }
        for (int j = t; j < K; j += 256) wk[j] = cw[j];
        __syncthreads();
        float y = cb[0];
        for (int j = 0; j < K; ++j) y += seg[t + j] * wk[j];
        adj[(size_t)b * S + s0 + t] = fmaxf(y, 0.f);
    }
}

// ---------------------------------------------------------------------------
// K2 (main): grid (S/64, B), block 256 = 4 waves.
// Wave w of block (bx, b): chunk c = bx*4+w, rows s in [c*16, c*16+16).
// 2-row groups staged into a wave-private 3-buffer LDS ring via
// global_load_lds; counted vmcnt(8) waits; compute = ds_read_b128 + the
// R3-verified 4-chain shfl butterfly. No __syncthreads in this kernel.
// ---------------------------------------------------------------------------
#define STAGE(buf, g)                                                        \
    {                                                                        \
        const float4* gs = row4 + (size_t)(2 * (g)) * rstride;               \
        float4* ld = (float4*)&lds4[wave][(buf)][0];                         \
        gll16(gs + lane, ld);                                                \
        gll16(gs + lane + 64, ld + 64);                                      \
        gll16(gs + rstride + lane, ld + 128);                                \
        gll16(gs + rstride + lane + 64, ld + 192);                           \
    }

#define WAITV(n) asm volatile("s_waitcnt vmcnt(" #n ")" ::: "memory")

#define COMPUTE(buf, g, C0, C1)                                              \
    {                                                                        \
        const float4* ld = (const float4*)&lds4[wave][(buf)][0];             \
        float4 xa0 = ld[lane];                                               \
        float4 xa1 = ld[lane + 64];                                          \
        float4 xb0 = ld[lane + 128];                                         \
        float4 xb1 = ld[lane + 192];                                         \
        float dota = xa0.x * ns0.x + xa0.y * ns0.y + xa0.z * ns0.z           \
                   + xa0.w * ns0.w + xa1.x * ns1.x + xa1.y * ns1.y           \
                   + xa1.z * ns1.z + xa1.w * ns1.w;                          \
        float sqa  = xa0.x * xa0.x + xa0.y * xa0.y + xa0.z * xa0.z           \
                   + xa0.w * xa0.w + xa1.x * xa1.x + xa1.y * xa1.y           \
                   + xa1.z * xa1.z + xa1.w * xa1.w;                          \
        float dotb = xb0.x * ns0.x + xb0.y * ns0.y + xb0.z * ns0.z           \
                   + xb0.w * ns0.w + xb1.x * ns1.x + xb1.y * ns1.y           \
                   + xb1.z * ns1.z + xb1.w * ns1.w;                          \
        float sqb  = xb0.x * xb0.x + xb0.y * xb0.y + xb0.z * xb0.z           \
                   + xb0.w * xb0.w + xb1.x * xb1.x + xb1.y * xb1.y           \
                   + xb1.z * xb1.z + xb1.w * xb1.w;                          \
        _Pragma("unroll")                                                    \
        for (int off = 32; off; off >>= 1) {                                 \
            dota += __shfl_xor(dota, off);                                   \
            dotb += __shfl_xor(dotb, off);                                   \
            sqa  += __shfl_xor(sqa, off);                                    \
            sqb  += __shfl_xor(sqb, off);                                    \
        }                                                                    \
        float ra = (sqa > 0.f) ? __builtin_amdgcn_rsqf(sqa) : 0.f;           \
        float rb = (sqb > 0.f) ? __builtin_amdgcn_rsqf(sqb) : 0.f;           \
        float c0 = __shfl(adjv, 2 * (g)) * __expf(dota * ra);                \
        float c1 = __shfl(adjv, 2 * (g) + 1) * __expf(dotb * rb);            \
        C0 = c0;                                                             \
        C1 = c1;                                                             \
        acc0.x += c0 * xa0.x + c1 * xb0.x;                                   \
        acc0.y += c0 * xa0.y + c1 * xb0.y;                                   \
        acc0.z += c0 * xa0.z + c1 * xb0.z;                                   \
        acc0.w += c0 * xa0.w + c1 * xb0.w;                                   \
        acc1.x += c0 * xa1.x + c1 * xb1.x;                                   \
        acc1.y += c0 * xa1.y + c1 * xb1.y;                                   \
        acc1.z += c0 * xa1.z + c1 * xb1.z;                                   \
        acc1.w += c0 * xa1.w + c1 * xb1.w;                                   \
        z += c0 + c1;                                                        \
    }

__global__ __launch_bounds__(256) void main_kernel(
    const float* __restrict__ e, const float* __restrict__ ns,
    const float* __restrict__ adj, float* __restrict__ partial,
    float* __restrict__ zbuf, float* __restrict__ u,
    int S, int B, int D) {
    constexpr int CH = 16;
    // per-wave 3-buffer ring: [wave][buf][2 rows x 128 float4] = 48 KB/block
    __shared__ __align__(16) float4 lds4[4][3][256];
    int wave = threadIdx.x >> 6;
    int lane = threadIdx.x & 63;
    int c = blockIdx.x * 4 + wave;
    int b = blockIdx.y;
    int NCH = gridDim.x * 4;      // chunks per batch row
    int s0 = c * CH;

    const float4* ns4 = (const float4*)(ns + (size_t)b * D);
    float4 ns0 = ns4[lane];
    float4 ns1 = ns4[lane + 64];
    float adjv = (lane < CH) ? adj[(size_t)b * S + s0 + lane] : 0.f;

    float4 acc0 = {0.f, 0.f, 0.f, 0.f};
    float4 acc1 = {0.f, 0.f, 0.f, 0.f};
    float z = 0.f;
    float4 up0, up1, up2, up3;    // packed u coefs (lane 0 stores at end)

    const float4* row4 = (const float4*)(e + ((size_t)s0 * B + b) * D);
    size_t rstride = (size_t)B * D / 4;   // float4 stride between s rows

    // prologue: 3 groups in flight (12 loads)
    STAGE(0, 0)
    STAGE(1, 1)
    STAGE(2, 2)
    // steady state: wait vmcnt(8) -> group ready; compute; refill ring.
    WAITV(8); COMPUTE(0, 0, up0.x, up0.y) STAGE(0, 3)
    WAITV(8); COMPUTE(1, 1, up0.z, up0.w) STAGE(1, 4)
    WAITV(8); COMPUTE(2, 2, up1.x, up1.y) STAGE(2, 5)
    WAITV(8); COMPUTE(0, 3, up1.z, up1.w) STAGE(0, 6)
    WAITV(8); COMPUTE(1, 4, up2.x, up2.y) STAGE(1, 7)
    WAITV(8); COMPUTE(2, 5, up2.z, up2.w)
    WAITV(4); COMPUTE(0, 6, up3.x, up3.y)
    WAITV(0); COMPUTE(1, 7, up3.z, up3.w)

    if (lane == 0) {
        float4* up = (float4*)(u + (size_t)b * S + s0);
        up[0] = up0; up[1] = up1; up[2] = up2; up[3] = up3;
        zbuf[(size_t)b * NCH + c] = z;
    }
    // per-wave partial: partial[b][c][:] (contiguous for combine)
    float4* p4 = (float4*)(partial + ((size_t)b * NCH + c) * D);
    p4[lane] = acc0;
    p4[lane + 64] = acc1;
}

// ---------------------------------------------------------------------------
// K3: grid (4, B), block 256. Block (q,b):
//   Z = sum_c zbuf[b][c]  (NPART<=256: one per thread, block reduce)
//   applied[b, q*128 .. +128) = sum_c partial[b][c][slice] / Z
//   norm_w[b, q*512 .. +512) = u[...] / Z
// ---------------------------------------------------------------------------
__global__ __launch_bounds__(256) void combine_kernel(
    const float* __restrict__ partial, const float* __restrict__ zbuf,
    const float* __restrict__ u, float* __restrict__ applied,
    float* __restrict__ norm_w, int S, int B, int D, int NPART) {
    int q = blockIdx.x;       // 0..3
    int b = blockIdx.y;
    int t = threadIdx.x;
    __shared__ __align__(16) float4 red4[8][32];
    __shared__ float zred[4];
    __shared__ float zsh;

    // Z reduce: one zbuf entry per thread (NPART <= 256), block reduce
    float zt = (t < NPART) ? zbuf[(size_t)b * NPART + t] : 0.f;
    zt = wave_sum(zt);
    if ((t & 63) == 0) zred[t >> 6] = zt;

    // applied quarter: 32 float4 columns, 8-way chunk strata across threads
    int c2 = t >> 5;          // 0..7
    int di = t & 31;          // 0..31
    int d4 = q * 32 + di;     // float4 index into D/4 = 128
    const float4* p4 = (const float4*)partial;
    float4 a = {0.f, 0.f, 0.f, 0.f};
    for (int cix = c2; cix < NPART; cix += 8) {
        float4 x = p4[((size_t)b * NPART + cix) * (D >> 2) + d4];
        a.x += x.x; a.y += x.y; a.z += x.z; a.w += x.w;
    }
    red4[c2][di] = a;
    __syncthreads();
    if (t == 0) zsh = 1.f / (zred[0] + zred[1] + zred[2] + zred[3]);
    __syncthreads();
    float inv = zsh;
    if (t < 32) {
        float4 s = red4[0][t];
#pragma unroll
        for (int j = 1; j < 8; ++j) {
            float4 x = red4[j][t];
            s.x += x.x; s.y += x.y; s.z += x.z; s.w += x.w;
        }
        s.x *= inv; s.y *= inv; s.z *= inv; s.w *= inv;
        ((float4*)(applied + (size_t)b * D))[q * 32 + t] = s;
    }

    // norm_w quarter: 128 float4 per q-slice
    const float4* u4 = (const float4*)(u + (size_t)b * S);
    float4* nw4 = (float4*)(norm_w + (size_t)b * S);
    if (t < 128) {
        int idx = q * (S >> 4) + t;   // S/4 float4 per b, quarter = S/16
        float4 x = u4[idx];
        x.x *= inv; x.y *= inv; x.z *= inv; x.w *= inv;
        nw4[idx] = x;
    }
}

extern "C" void kernel_launch(void* const* d_in, const int* in_sizes, int n_in,
                              void* d_out, int out_size, void* d_ws, size_t ws_size,
                              hipStream_t stream) {
    const float* enc   = (const float*)d_in[0];  // [S,B,D]
    const float* state = (const float*)d_in[1];  // [B,D]
    const float* prev  = (const float*)d_in[2];  // [B,S]
    const float* W     = (const float*)d_in[3];  // [D,D]
    const float* bias  = (const float*)d_in[4];  // [D]
    const float* cw    = (const float*)d_in[5];  // [K]
    const float* cb    = (const float*)d_in[6];  // [1]

    const int S = in_sizes[0] / in_sizes[1];   // 2048
    const int B = in_sizes[2] / S;             // 32
    const int D = in_sizes[1] / B;             // 512
    const int K = in_sizes[5];                 // 147

    float* out     = (float*)d_out;
    float* applied = out;                    // B*D
    float* norm_w  = out + (size_t)B * D;    // B*S

    const int CH = 16;             // s-rows per wave (matches kernel constexpr)
    const int NPART = S / CH;      // 128 per-wave partials per batch row

    float* ws       = (float*)d_ws;
    float* nsbuf    = ws;                            // B*D
    float* adj      = nsbuf + (size_t)B * D;         // B*S
    float* u        = adj + (size_t)B * S;           // B*S
    float* zbuf     = u + (size_t)B * S;             // B*NPART
    float* partial  = zbuf + (size_t)B * NPART;      // B*NPART*D (8.4 MB)

    front_kernel<<<dim3(1 + S / 256, B), 256, 0, stream>>>(
        state, W, bias, prev, cw, cb, nsbuf, adj, S, D, K);
    main_kernel<<<dim3(NPART / 4, B), 256, 0, stream>>>(
        enc, nsbuf, adj, partial, zbuf, u, S, B, D);
    combine_kernel<<<dim3(4, B), 256, 0, stream>>>(
        partial, zbuf, u, applied, norm_w, S, B, D, NPART);
}

// Round 7
// 210.883 us; speedup vs baseline: 1.3087x; 1.1896x over previous
//
#include <hip/hip_runtime.h>
#include <math.h>

// ---------------------------------------------------------------------------
// TimeAttender: S=2048, B=32, D=512, K=147
// out = concat(applied [B*D], norm_w [B*S])
//
// Math notes:
//  * prev_probs normalizer and softmax Z cancel in
//      norm_w = adj * exp(w) / sum_s(adj * exp(w))
//  * w is a cosine similarity in [-1,1] -> exp(w) in [0.37, 2.72]:
//    no max-subtraction needed; apply pass is single-pass over e.
//  * SESSION LEDGER (R0..R6) — read before "optimizing":
//    - Fixed harness cost ~157 us (512 MiB poison fills + resets) dominates.
//    - Best = THIS structure (R1, 220.0 us). R3 (2-row ILP, CH=8) = 221.7.
//    - R2: last-block fusion w/ __threadfence = L2-writeback storm (+55).
//    - R4: contiguous-vs-strided e walk: NEUTRAL-to-worse (+28 w/ combine
//      side effects). Access pattern is NOT the limiter.
//    - R5: register-resident 16-row pipeline: VGPR spills, WRITE_SIZE
//      85.8 MB (+56). Deep pipelines don't fit in VGPRs here.
//    - R6: global_load_lds 3-buffer ring + counted vmcnt: +29. Compiler
//      conservatively drains vmcnt before ds_reads aliasing the DMA target
//      (documented trap, guide §5 m131-m141); ring degenerated to serial.
//    - main is pinned at ~50 us (~2.5 TB/s effective) across FIVE
//      structurally independent variants; occupancy/ILP/contiguity all
//      experimentally excluded. Do not bet on main structure again.
//  * This round: R1 verbatim + NON-TEMPORAL loads on the e stream (134 MB
//    read-once): keeps the dead stream from evicting W/ns/adj/partial/u
//    (the ~5 MB of reused data) out of L2.
// ---------------------------------------------------------------------------

typedef float f32x4_t __attribute__((ext_vector_type(4)));

__device__ __forceinline__ float4 ntload4(const float4* p) {
    f32x4_t v = __builtin_nontemporal_load((const f32x4_t*)p);
    float4 r;
    r.x = v[0]; r.y = v[1]; r.z = v[2]; r.w = v[3];
    return r;
}

__device__ __forceinline__ float wave_sum(float v) {
    for (int off = 32; off; off >>= 1) v += __shfl_xor(v, off);
    return v;
}

// ---------------------------------------------------------------------------
// K1: grid (2 + S/256, B), block 256. Role split on blockIdx.x:
//   bx < 2      : attended[b, bx*256+t] = dot(state[b,:], W[d,:]) + bias[d]
//   bx >= 2     : adj[b, s] = relu(conv1d_same(prev[b,:], cw)[s] + cb0)
// ---------------------------------------------------------------------------
__global__ __launch_bounds__(256) void front_kernel(
    const float* __restrict__ state, const float* __restrict__ W,
    const float* __restrict__ bias, const float* __restrict__ prev,
    const float* __restrict__ cw, const float* __restrict__ cb,
    float* __restrict__ attended, float* __restrict__ adj,
    int S, int D, int K) {
    __shared__ __align__(16) float smem[1024];
    int b = blockIdx.y;
    int t = threadIdx.x;

    if (blockIdx.x < 2) {
        // ---- linear part ----
        if (t < D / 4)
            ((float4*)smem)[t] = ((const float4*)(state + (size_t)b * D))[t];
        __syncthreads();
        int d = blockIdx.x * 256 + t;
        const float4* Wrow = (const float4*)(W + (size_t)d * D);
        const float4* sv = (const float4*)smem;
        float acc = bias[d];
#pragma unroll 8
        for (int k = 0; k < 128; ++k) {
            float4 w4 = Wrow[k];
            float4 s4 = sv[k];
            acc += w4.x * s4.x + w4.y * s4.y + w4.z * s4.z + w4.w * s4.w;
        }
        attended[(size_t)b * D + d] = acc;
    } else {
        // ---- conv part ----
        int s0 = (blockIdx.x - 2) * 256;
        int pad = K / 2;
        int seglen = 256 + K - 1;
        float* seg = smem;            // seglen floats (<= 256+255)
        float* wk = smem + 512;       // K floats (<= 256)
        for (int i = t; i < seglen; i += 256) {
            int s = s0 - pad + i;
            seg[i] = (s >= 0 && s < S) ? prev[(size_t)b * S + s] : 0.f;
        }
        for (int j = t; j < K; j += 256) wk[j] = cw[j];
        __syncthreads();
        float y = cb[0];
        for (int j = 0; j < K; ++j) y += seg[t + j] * wk[j];
        adj[(size_t)b * S + s0 + t] = fmaxf(y, 0.f);
    }
}

// ---------------------------------------------------------------------------
// K2 (main, single e pass): grid (NCB/4, B), block 256 = 4 waves.
// Each WAVE owns chunk c = bx*4+wave of CH consecutive s for batch b:
//   - recompute ns[b,:] slice in registers from attended (2 KB, L2-hot)
//   - per row: w = dot(ns,e_row)/||e_row||; coef = adj*exp(w)
//              acc += coef*row; z += coef; u[b,s] = coef
// Then the block's 4 waves reduce acc/z through LDS -> ONE partial per block.
// e loads are NON-TEMPORAL (read-once stream, keep L2 for reused data).
// ---------------------------------------------------------------------------
__global__ __launch_bounds__(256) void main_kernel(
    const float* __restrict__ e, const float* __restrict__ attended,
    const float* __restrict__ adj, float* __restrict__ partial,
    float* __restrict__ zbuf, float* __restrict__ u,
    int S, int B, int D, int CH) {
    __shared__ __align__(16) float reds[4 * 512 + 4];   // 4 wave slices + 4 z
    int wave = threadIdx.x >> 6;
    int lane = threadIdx.x & 63;
    int c = blockIdx.x * 4 + wave;
    int b = blockIdx.y;

    // ns slice for this lane (d = lane*4.. and d = 256+lane*4..)
    const float4* att4 = (const float4*)(attended + (size_t)b * D);
    float4 a0 = att4[lane];
    float4 a1 = att4[lane + 64];
    float asq = a0.x * a0.x + a0.y * a0.y + a0.z * a0.z + a0.w * a0.w
              + a1.x * a1.x + a1.y * a1.y + a1.z * a1.z + a1.w * a1.w;
    asq = wave_sum(asq);
    float an = sqrtf(asq);
    if (an == 0.f) an = 1e-10f;
    float ainv = 1.f / an;
    float4 ns0, ns1;
    ns0.x = a0.x * ainv; ns0.y = a0.y * ainv; ns0.z = a0.z * ainv; ns0.w = a0.w * ainv;
    ns1.x = a1.x * ainv; ns1.y = a1.y * ainv; ns1.z = a1.z * ainv; ns1.w = a1.w * ainv;

    int s0 = c * CH;

    // preload the chunk's adj values (uniform per row); shfl per row
    float adjv = 0.f;
    if (CH <= 64 && lane < CH) adjv = adj[(size_t)b * S + s0 + lane];

    float4 acc0 = {0.f, 0.f, 0.f, 0.f};
    float4 acc1 = {0.f, 0.f, 0.f, 0.f};
    float z = 0.f;

    const float4* row4 = (const float4*)(e + ((size_t)s0 * B + b) * D);
    size_t rstride = (size_t)B * D / 4;  // float4 stride between s rows

    float4 x0 = ntload4(row4 + lane);
    float4 x1 = ntload4(row4 + lane + 64);
    for (int i = 0; i < CH; ++i) {
        float4 nx0, nx1;
        if (i + 1 < CH) {
            nx0 = ntload4(row4 + rstride + lane);
            nx1 = ntload4(row4 + rstride + lane + 64);
        }
        float dot = x0.x * ns0.x + x0.y * ns0.y + x0.z * ns0.z + x0.w * ns0.w
                  + x1.x * ns1.x + x1.y * ns1.y + x1.z * ns1.z + x1.w * ns1.w;
        float sq  = x0.x * x0.x + x0.y * x0.y + x0.z * x0.z + x0.w * x0.w
                  + x1.x * x1.x + x1.y * x1.y + x1.z * x1.z + x1.w * x1.w;
        dot = wave_sum(dot);
        sq  = wave_sum(sq);
        float n = sqrtf(sq);
        if (n == 0.f) n = 1e-10f;
        float w = dot / n;
        float av = (CH <= 64) ? __shfl(adjv, i) : adj[(size_t)b * S + s0 + i];
        float coef = av * __expf(w);
        if (lane == 0) u[(size_t)b * S + s0 + i] = coef;
        acc0.x += coef * x0.x; acc0.y += coef * x0.y;
        acc0.z += coef * x0.z; acc0.w += coef * x0.w;
        acc1.x += coef * x1.x; acc1.y += coef * x1.y;
        acc1.z += coef * x1.z; acc1.w += coef * x1.w;
        z += coef;
        x0 = nx0; x1 = nx1;
        row4 += rstride;
    }

    // ---- block-level reduction: 4 wave-chunks -> 1 block partial ----
    float* wsl = reds + (wave << 9);           // 512 floats per wave
    ((float4*)wsl)[lane] = acc0;               // d in [0,256)
    ((float4*)wsl)[lane + 64] = acc1;          // d in [256,512)
    if (lane == 0) reds[2048 + wave] = z;      // coef is wave-uniform: z full
    __syncthreads();
    int t = threadIdx.x;
    if (t < 128) {
        const float4* r4 = (const float4*)reds;
        float4 v0 = r4[t];
        float4 v1 = r4[t + 128];
        float4 v2 = r4[t + 256];
        float4 v3 = r4[t + 384];
        float4 o;
        o.x = v0.x + v1.x + v2.x + v3.x;
        o.y = v0.y + v1.y + v2.y + v3.y;
        o.z = v0.z + v1.z + v2.z + v3.z;
        o.w = v0.w + v1.w + v2.w + v3.w;
        ((float4*)(partial + ((size_t)blockIdx.x * B + b) * D))[t] = o;
    }
    if (t == 0)
        zbuf[(size_t)blockIdx.x * B + b] =
            reds[2048] + reds[2049] + reds[2050] + reds[2051];
}

// ---------------------------------------------------------------------------
// K3: grid (4, B), block 256. Block (q,b):
//   Z = sum_c zbuf[c][b]  (NPART<=64: lanes of wave 0)
//   applied[b, q*128 .. q*128+128) = sum_c partial[c][b][slice] / Z
//   norm_w[b, q*512 .. q*512+512) = u[...] / Z
// ---------------------------------------------------------------------------
__global__ __launch_bounds__(256) void combine_kernel(
    const float* __restrict__ partial, const float* __restrict__ zbuf,
    const float* __restrict__ u, float* __restrict__ applied,
    float* __restrict__ norm_w, int S, int B, int D, int NPART) {
    int q = blockIdx.x;       // 0..3
    int b = blockIdx.y;
    int t = threadIdx.x;
    __shared__ __align__(16) float4 red4[8][32];
    __shared__ float zsh;

    // Z reduce (wave 0, lanes < NPART)
    float zt = (t < NPART) ? zbuf[(size_t)t * B + b] : 0.f;
    zt = wave_sum(zt);
    if (t == 0) zsh = 1.f / zt;

    // applied quarter: 32 float4 outputs, 8-way chunk split across threads
    int c2 = t >> 5;          // 0..7
    int di = t & 31;          // 0..31
    int d4 = q * 32 + di;     // float4 index into D/4 = 128
    const float4* p4 = (const float4*)partial;
    float4 a = {0.f, 0.f, 0.f, 0.f};
    for (int cix = c2; cix < NPART; cix += 8) {
        float4 x = p4[((size_t)cix * B + b) * (D >> 2) + d4];
        a.x += x.x; a.y += x.y; a.z += x.z; a.w += x.w;
    }
    red4[c2][di] = a;
    __syncthreads();          // covers zsh too
    float inv = zsh;
    if (t < 32) {
        float4 s = red4[0][t];
#pragma unroll
        for (int j = 1; j < 8; ++j) {
            float4 x = red4[j][t];
            s.x += x.x; s.y += x.y; s.z += x.z; s.w += x.w;
        }
        s.x *= inv; s.y *= inv; s.z *= inv; s.w *= inv;
        ((float4*)(applied + (size_t)b * D))[q * 32 + t] = s;
    }

    // norm_w quarter: 128 float4 per q-slice
    const float4* u4 = (const float4*)(u + (size_t)b * S);
    float4* nw4 = (float4*)(norm_w + (size_t)b * S);
    if (t < 128) {
        int idx = q * (S >> 4) + t;   // S/4 float4 per b, quarter = S/16
        float4 x = u4[idx];
        x.x *= inv; x.y *= inv; x.z *= inv; x.w *= inv;
        nw4[idx] = x;
    }
}

extern "C" void kernel_launch(void* const* d_in, const int* in_sizes, int n_in,
                              void* d_out, int out_size, void* d_ws, size_t ws_size,
                              hipStream_t stream) {
    const float* enc   = (const float*)d_in[0];  // [S,B,D]
    const float* state = (const float*)d_in[1];  // [B,D]
    const float* prev  = (const float*)d_in[2];  // [B,S]
    const float* W     = (const float*)d_in[3];  // [D,D]
    const float* bias  = (const float*)d_in[4];  // [D]
    const float* cw    = (const float*)d_in[5];  // [K]
    const float* cb    = (const float*)d_in[6];  // [1]

    const int S = in_sizes[0] / in_sizes[1];   // 2048
    const int B = in_sizes[2] / S;             // 32
    const int D = in_sizes[1] / B;             // 512
    const int K = in_sizes[5];                 // 147

    float* out     = (float*)d_out;
    float* applied = out;                    // B*D
    float* norm_w  = out + (size_t)B * D;    // B*S

    const int NCHUNK = 128;       // wave-chunks per batch row
    const int CH = S / NCHUNK;    // 16 s-rows per wave-chunk
    const int NPART = NCHUNK / 4; // 32 block partials per batch row

    float* ws       = (float*)d_ws;
    float* attended = ws;                            // B*D
    float* adj      = attended + (size_t)B * D;      // B*S
    float* u        = adj + (size_t)B * S;           // B*S
    float* zbuf     = u + (size_t)B * S;             // NPART*B
    float* partial  = zbuf + (size_t)NPART * B;      // NPART*B*D

    front_kernel<<<dim3(2 + S / 256, B), 256, 0, stream>>>(
        state, W, bias, prev, cw, cb, attended, adj, S, D, K);
    main_kernel<<<dim3(NPART, B), 256, 0, stream>>>(
        enc, attended, adj, partial, zbuf, u, S, B, D, CH);
    combine_kernel<<<dim3(4, B), 256, 0, stream>>>(
        partial, zbuf, u, applied, norm_w, S, B, D, NPART);
}